// Round 6
// baseline (189.210 us; speedup 1.0000x reference)
//
#include <hip/hip_runtime.h>
#include <math.h>

// FrequencyAwareHierarchicalEmbedding, MI355X/gfx950 — round 6
//
// B*L = 409600, D = 128, H = 32.
// d_in: fine_ids i32, coarse_ids i32, fine_W[1000001*128] f32,
//       coarse_W[10001*128] f32, freq_W[1000001] f32, W1[257*32], b1[32],
//       W2[32], b2[1].
// d_out: fused[BL*128] f32, then adjusted_gate[BL] f32.
//
// Round-6 changes vs round 5 (169.6us):
//  * TWO positions per lane (p and p+64; 512 positions per 256-thread block).
//    The wave-uniform weight chunks (scalar path / K$) now feed 2x the fmacs:
//    duty cycle per s_load chunk doubles, scalar traffic per position halves.
//  * Row stream in 8-float groups (2 float4/row), one group prefetch-ahead,
//    16 groups — keeps VGPRs ~115 (h[64] + 32 stream regs) for 4 waves/SIMD.
//  * Phase 2 explicitly software-pipelined 1 iteration ahead.
//  * Retained: hc precompute, scalar weights, nontemporal output stores,
//    in-kernel fusion phase (L1/L2-hot row re-read).

#define DD 128
#define HH 32

typedef float f32x4 __attribute__((ext_vector_type(4)));

__device__ __forceinline__ float sigmoid_f(float x) {
    return 1.0f / (1.0f + expf(-x));
}

// ---------------------------------------------------------------- kernel A --
__global__ __launch_bounds__(256) void coarse_mlp_kernel(
    const float* __restrict__ coarse_W,
    const float* __restrict__ W1,
    const float* __restrict__ b1,
    float* __restrict__ hc,
    int nCoarse)
{
    const int t = blockIdx.x * 256 + threadIdx.x;
    if (t >= nCoarse * HH) return;
    const int r = t >> 5;
    const int j = t & 31;
    const float* __restrict__ row = coarse_W + (size_t)r * DD;
    const float* __restrict__ w   = W1 + DD * HH + j;   // coarse rows of W1
    float acc = b1[j];
    #pragma unroll 8
    for (int i = 0; i < DD; ++i)
        acc = fmaf(row[i], w[i * HH], acc);
    hc[t] = acc;
}

// ---------------------------------------------------------------- kernel B --
// 4 input elements from one float4; weights via wave-uniform scalar loads
__device__ __forceinline__ void acc4(float* __restrict__ h,
                                     const float* __restrict__ w, float4 v) {
    #pragma unroll
    for (int j = 0; j < HH; ++j) h[j] = fmaf(w[j], v.x, h[j]);
    #pragma unroll
    for (int j = 0; j < HH; ++j) h[j] = fmaf(w[HH + j], v.y, h[j]);
    #pragma unroll
    for (int j = 0; j < HH; ++j) h[j] = fmaf(w[2 * HH + j], v.z, h[j]);
    #pragma unroll
    for (int j = 0; j < HH; ++j) h[j] = fmaf(w[3 * HH + j], v.w, h[j]);
}

__global__ __launch_bounds__(256, 4) void fused_kernel(
    const int*   __restrict__ fine_ids,
    const int*   __restrict__ coarse_ids,
    const float* __restrict__ fine_W,
    const float* __restrict__ coarse_W,
    const float* __restrict__ freq_W,
    const float* __restrict__ W1,
    const float* __restrict__ W2,
    const float* __restrict__ b2,
    const float* __restrict__ hc,
    float* __restrict__ out_fused,
    float* __restrict__ out_gate)
{
    __shared__ float s_adj[512];
    __shared__ int   s_if[512];
    __shared__ int   s_ic[512];

    const int tid  = threadIdx.x;
    const int lane = tid & 63;
    const int wave = tid >> 6;
    const int P0   = (int)blockIdx.x * 512;
    const int slotA = wave * 128 + lane;      // this lane's two slots
    const int slotB = slotA + 64;
    const int pA = P0 + slotA;
    const int pB = P0 + slotB;

    // ---- ids + early gathers -------------------------------------------
    const int idfA = fine_ids[pA];
    const int idfB = fine_ids[pB];
    const int idcA = coarse_ids[pA];
    const int idcB = coarse_ids[pB];

    s_if[slotA] = idfA;  s_if[slotB] = idfB;
    s_ic[slotA] = idcA;  s_ic[slotB] = idcB;

    const float4* __restrict__ rowA = (const float4*)(fine_W + (size_t)idfA * DD);
    const float4* __restrict__ rowB = (const float4*)(fine_W + (size_t)idfB * DD);

    // first 8-float group for each row
    float4 xA0 = rowA[0], xA1 = rowA[1];
    float4 xB0 = rowB[0], xB1 = rowB[1];

    const float frawA = freq_W[idfA];
    const float frawB = freq_W[idfB];

    float hA[HH], hB[HH];
    {
        const float4* __restrict__ hA4 = (const float4*)(hc + idcA * HH);
        const float4* __restrict__ hB4 = (const float4*)(hc + idcB * HH);
        #pragma unroll
        for (int g = 0; g < 8; ++g) {
            const float4 va = hA4[g];
            hA[4 * g + 0] = va.x; hA[4 * g + 1] = va.y;
            hA[4 * g + 2] = va.z; hA[4 * g + 3] = va.w;
            const float4 vb = hB4[g];
            hB[4 * g + 0] = vb.x; hB[4 * g + 1] = vb.y;
            hB[4 * g + 2] = vb.z; hB[4 * g + 3] = vb.w;
        }
    }
    const float fwA = sigmoid_f(frawA);
    const float fwB = sigmoid_f(frawB);

    // ---- phase 1: fine_emb @ W1[0..127], 16 groups of 8 floats ---------
    #pragma unroll 1
    for (int g = 0; g < 16; ++g) {
        float4 nA0, nA1, nB0, nB1;
        if (g < 15) {
            nA0 = rowA[2 * g + 2]; nA1 = rowA[2 * g + 3];
            nB0 = rowB[2 * g + 2]; nB1 = rowB[2 * g + 3];
        }
        const float* __restrict__ w = W1 + g * 8 * HH;   // wave-uniform
        acc4(hA, w,          xA0);
        acc4(hB, w,          xB0);
        acc4(hA, w + 4 * HH, xA1);
        acc4(hB, w + 4 * HH, xB1);
        xA0 = nA0; xA1 = nA1; xB0 = nB0; xB1 = nB1;
    }

    // freq feature (W1 row 256) — wave-uniform
    {
        const float* __restrict__ w = W1 + 2 * DD * HH;
        #pragma unroll
        for (int j = 0; j < HH; ++j) {
            hA[j] = fmaf(w[j], fwA, hA[j]);
            hB[j] = fmaf(w[j], fwB, hB[j]);
        }
    }

    // gate = sigmoid(relu(h) @ W2 + b2); adjusted = gate * fw
    float sA = b2[0], sB = b2[0];
    #pragma unroll
    for (int j = 0; j < HH; ++j) {
        sA = fmaf(fmaxf(hA[j], 0.0f), W2[j], sA);
        sB = fmaf(fmaxf(hB[j], 0.0f), W2[j], sB);
    }
    const float adjA = sigmoid_f(sA) * fwA;
    const float adjB = sigmoid_f(sB) * fwB;

    __builtin_nontemporal_store(adjA, out_gate + pA);
    __builtin_nontemporal_store(adjB, out_gate + pB);
    s_adj[slotA] = adjA;
    s_adj[slotB] = adjB;
    __syncthreads();

    // ---- phase 2: fusion, wave-cooperative, float4, pipelined 1-ahead ---
    const int half = lane >> 5;          // 0/1: which slot of the pair
    const int d0   = (lane & 31) * 4;    // 32 lanes cover the 128-float row
    const int wslot = wave * 128;

    int    slotP = wslot + half;
    float  aP = s_adj[slotP];
    int    jfP = s_if[slotP] * DD;
    int    jcP = s_ic[slotP] * DD;
    float4 fP = *(const float4*)(fine_W   + jfP + d0);
    float4 cP = *(const float4*)(coarse_W + jcP + d0);

    #pragma unroll 1
    for (int q = 0; q < 128; q += 2) {
        const float  a = aP;
        const float4 f = fP;
        const float4 c = cP;
        const int slotC = wslot + q + half;
        if (q + 2 < 128) {
            const int s2 = wslot + q + 2 + half;
            aP  = s_adj[s2];
            jfP = s_if[s2] * DD;
            jcP = s_ic[s2] * DD;
            fP  = *(const float4*)(fine_W   + jfP + d0);   // L1/L2 hit
            cP  = *(const float4*)(coarse_W + jcP + d0);   // L2-resident
        }
        f32x4 o;
        o.x = fmaf(a, f.x - c.x, c.x);
        o.y = fmaf(a, f.y - c.y, c.y);
        o.z = fmaf(a, f.z - c.z, c.z);
        o.w = fmaf(a, f.w - c.w, c.w);
        f32x4* dst = (f32x4*)(out_fused + (size_t)(P0 + slotC) * DD + d0);
        __builtin_nontemporal_store(o, dst);          // never re-read
    }
}

// ------------------------------------------------------------------- launch --
extern "C" void kernel_launch(void* const* d_in, const int* in_sizes, int n_in,
                              void* d_out, int out_size, void* d_ws, size_t ws_size,
                              hipStream_t stream) {
    const int*   fine_ids   = (const int*)  d_in[0];
    const int*   coarse_ids = (const int*)  d_in[1];
    const float* fine_W     = (const float*)d_in[2];
    const float* coarse_W   = (const float*)d_in[3];
    const float* freq_W     = (const float*)d_in[4];
    const float* W1         = (const float*)d_in[5];
    const float* b1         = (const float*)d_in[6];
    const float* W2         = (const float*)d_in[7];
    const float* b2         = (const float*)d_in[8];

    const int n       = in_sizes[0];          // B*L = 409600 (divisible by 512)
    const int nCoarse = in_sizes[3] / DD;     // 10001

    float* out_fused = (float*)d_out;
    float* out_gate  = (float*)d_out + (size_t)n * DD;
    float* hc        = (float*)d_ws;          // nCoarse*32 floats = 1.28 MB

    coarse_mlp_kernel<<<dim3((nCoarse * HH + 255) / 256), dim3(256), 0, stream>>>(
        coarse_W, W1, b1, hc, nCoarse);

    fused_kernel<<<dim3(n / 512), dim3(256), 0, stream>>>(
        fine_ids, coarse_ids, fine_W, coarse_W, freq_W,
        W1, W2, b2, hc, out_fused, out_gate);
}

// Round 7
// 141.391 us; speedup vs baseline: 1.3382x; 1.3382x over previous
//
#include <hip/hip_runtime.h>
#include <math.h>

// FrequencyAwareHierarchicalEmbedding, MI355X/gfx950 — round 7
//
// B*L = 409600, D = 128, H = 32.
// d_in: fine_ids i32, coarse_ids i32, fine_W[1000001*128] f32,
//       coarse_W[10001*128] f32, freq_W[1000001] f32, W1[257*32], b1[32],
//       W2[32], b2[1].
// d_out: fused[BL*128] f32, then adjusted_gate[BL] f32.
//
// Round-7 structure (pivot):
//  * Cooperative COALESCED staging of fine rows: one wave-instruction per row
//    (64 lanes x float2 = 512B contiguous), bf16-convert, XOR-swizzled LDS
//    tile (byte ^= (row&7)<<4) -> conflict-free ds_write/ds_read_b128.
//  * MLP1 on MFMA 16x16x32_bf16: X(128x128) @ W1fine(128x32). W1 B-fragments
//    built ONCE into 32 VGPRs, held all kernel (no per-wave weight stream).
//  * hc precompute (f32, exact) added in epilogue; freq row + W2 + b2 in the
//    epilogue with a 16-lane shfl_xor butterfly (C layout: col=lane&15,
//    row=(lane>>4)*4+reg — HW-verified mapping).
//  * Phase 2 fusion identical to round 5 (f32 path, nontemporal stores).

#define DD 128
#define HH 32

typedef float  f32x4  __attribute__((ext_vector_type(4)));
typedef short  bf16x8 __attribute__((ext_vector_type(8)));

__device__ __forceinline__ float sigmoid_f(float x) {
    return 1.0f / (1.0f + expf(-x));
}

__device__ __forceinline__ unsigned short bf16_rne(float x) {
    union { float f; unsigned u; } c; c.f = x;
    unsigned u = c.u + 0x7fffu + ((c.u >> 16) & 1u);
    return (unsigned short)(u >> 16);
}

// ---------------------------------------------------------------- kernel A --
__global__ __launch_bounds__(256) void coarse_mlp_kernel(
    const float* __restrict__ coarse_W,
    const float* __restrict__ W1,
    const float* __restrict__ b1,
    float* __restrict__ hc,
    int nCoarse)
{
    const int t = blockIdx.x * 256 + threadIdx.x;
    if (t >= nCoarse * HH) return;
    const int r = t >> 5;
    const int j = t & 31;
    const float* __restrict__ row = coarse_W + (size_t)r * DD;
    const float* __restrict__ w   = W1 + DD * HH + j;   // coarse rows of W1
    float acc = b1[j];
    #pragma unroll 8
    for (int i = 0; i < DD; ++i)
        acc = fmaf(row[i], w[i * HH], acc);
    hc[t] = acc;
}

// ---------------------------------------------------------------- kernel B --
__global__ __launch_bounds__(256, 3) void fused_kernel(
    const int*   __restrict__ fine_ids,
    const int*   __restrict__ coarse_ids,
    const float* __restrict__ fine_W,
    const float* __restrict__ coarse_W,
    const float* __restrict__ freq_W,
    const float* __restrict__ W1,
    const float* __restrict__ W2,
    const float* __restrict__ b2,
    const float* __restrict__ hc,
    float* __restrict__ out_fused,
    float* __restrict__ out_gate)
{
    __shared__ __align__(16) unsigned int sX[8192];   // 32KB: 128 rows x 256B (bf16)
    __shared__ float s_adj[256];
    __shared__ float s_fw[256];
    __shared__ int   s_if[256];
    __shared__ int   s_ic[256];

    const int tid  = threadIdx.x;
    const int lane = tid & 63;
    const int wave = tid >> 6;
    const int P0   = (int)blockIdx.x * 256;

    const int jlo = lane & 15;
    const int kg  = lane >> 4;          // 0..3

    // ---- metadata: ids + freq sigmoid (one position per thread) ---------
    {
        const int p = P0 + tid;
        const int idf = fine_ids[p];
        const int idc = coarse_ids[p];
        const float fr = freq_W[idf];
        s_if[tid] = idf;
        s_ic[tid] = idc;
        s_fw[tid] = sigmoid_f(fr);
    }

    // ---- W1 fine-half B-fragments -> 32 VGPRs, held all kernel ----------
    // B[k][j]: lane holds j = jlo+16n, k = ks*32 + kg*8 + i (i contiguous)
    bf16x8 bfr[2][4];
    #pragma unroll
    for (int n = 0; n < 2; ++n)
        #pragma unroll
        for (int ks = 0; ks < 4; ++ks)
            #pragma unroll
            for (int i = 0; i < 8; ++i) {
                const int k = ks * 32 + kg * 8 + i;
                bfr[n][ks][i] = (short)bf16_rne(W1[k * HH + jlo + 16 * n]);
            }

    // per-lane epilogue constants
    const float w256_0 = W1[2 * DD * HH + jlo];
    const float w256_1 = W1[2 * DD * HH + jlo + 16];
    const float W2_0   = W2[jlo];
    const float W2_1   = W2[jlo + 16];
    const float b2v    = b2[0];

    __syncthreads();

    // ---- halves: stage 128 rows -> MFMA+epilogue ------------------------
    #pragma unroll 1
    for (int h = 0; h < 2; ++h) {
        const int hbase = h * 128;

        // stage: wave stages rows [wave*32, wave*32+32); one row per instr
        #pragma unroll 4
        for (int it = 0; it < 32; ++it) {
            const int rr  = wave * 32 + it;
            const int idf = s_if[hbase + rr];            // LDS broadcast
            const float2 v = *(const float2*)(fine_W + (size_t)idf * DD + 2 * lane);
            const unsigned pk = (unsigned)bf16_rne(v.x)
                              | ((unsigned)bf16_rne(v.y) << 16);
            *(unsigned*)((char*)sX + rr * 256 + ((4 * lane) ^ ((rr & 7) << 4))) = pk;
        }
        __syncthreads();

        // MFMA: wave handles m-tiles {wave*2, wave*2+1}
        #pragma unroll 1
        for (int mt2 = 0; mt2 < 2; ++mt2) {
            const int mt    = wave * 2 + mt2;
            const int rbase = mt * 16;
            f32x4 acc0 = {0.f, 0.f, 0.f, 0.f};
            f32x4 acc1 = {0.f, 0.f, 0.f, 0.f};
            const int rr = rbase + jlo;                  // A row for this lane
            #pragma unroll
            for (int ks = 0; ks < 4; ++ks) {
                const bf16x8 a = *(const bf16x8*)((const char*)sX
                    + rr * 256 + ((kg * 16 + ks * 64) ^ ((rr & 7) << 4)));
                acc0 = __builtin_amdgcn_mfma_f32_16x16x32_bf16(a, bfr[0][ks], acc0, 0, 0, 0);
                acc1 = __builtin_amdgcn_mfma_f32_16x16x32_bf16(a, bfr[1][ks], acc1, 0, 0, 0);
            }
            // epilogue: + hc + freq row, relu, @W2, butterfly, sigmoid
            #pragma unroll
            for (int r = 0; r < 4; ++r) {
                const int posl = hbase + rbase + kg * 4 + r;   // local 0..255
                const int idc  = s_ic[posl];
                const float fw = s_fw[posl];
                const float* __restrict__ hcrow = hc + idc * HH;
                const float v0 = acc0[r] + hcrow[jlo]      + w256_0 * fw;
                const float v1 = acc1[r] + hcrow[jlo + 16] + w256_1 * fw;
                float tr = fmaxf(v0, 0.f) * W2_0 + fmaxf(v1, 0.f) * W2_1;
                tr += __shfl_xor(tr, 1);
                tr += __shfl_xor(tr, 2);
                tr += __shfl_xor(tr, 4);
                tr += __shfl_xor(tr, 8);
                const float adj = sigmoid_f(tr + b2v) * fw;
                if (jlo == r) s_adj[posl] = adj;
            }
        }
        __syncthreads();    // sX free for next half / s_adj visible at end
    }

    // ---- gate output (coalesced) ---------------------------------------
    __builtin_nontemporal_store(s_adj[tid], out_gate + P0 + tid);

    // ---- phase 2: fusion, wave-cooperative (round-5 proven) -------------
    const int half = lane >> 5;          // 0/1: which slot of the pair
    const int d0   = (lane & 31) * 4;    // 32 lanes cover the 128-float row
    const int waveBase = wave * 64;
    #pragma unroll 1
    for (int q = 0; q < 64; q += 2) {
        const int slot = waveBase + q + half;
        const float a  = s_adj[slot];
        const int   jf = s_if[slot] * DD;
        const int   jc = s_ic[slot] * DD;
        const float4 f = *(const float4*)(fine_W   + (size_t)jf + d0);  // L1/L2 hit
        const float4 c = *(const float4*)(coarse_W + (size_t)jc + d0);  // L2-resident
        f32x4 o;
        o.x = fmaf(a, f.x - c.x, c.x);
        o.y = fmaf(a, f.y - c.y, c.y);
        o.z = fmaf(a, f.z - c.z, c.z);
        o.w = fmaf(a, f.w - c.w, c.w);
        f32x4* dst = (f32x4*)(out_fused + (size_t)(P0 + slot) * DD + d0);
        __builtin_nontemporal_store(o, dst);          // never re-read
    }
}

// ------------------------------------------------------------------- launch --
extern "C" void kernel_launch(void* const* d_in, const int* in_sizes, int n_in,
                              void* d_out, int out_size, void* d_ws, size_t ws_size,
                              hipStream_t stream) {
    const int*   fine_ids   = (const int*)  d_in[0];
    const int*   coarse_ids = (const int*)  d_in[1];
    const float* fine_W     = (const float*)d_in[2];
    const float* coarse_W   = (const float*)d_in[3];
    const float* freq_W     = (const float*)d_in[4];
    const float* W1         = (const float*)d_in[5];
    const float* b1         = (const float*)d_in[6];
    const float* W2         = (const float*)d_in[7];
    const float* b2         = (const float*)d_in[8];

    const int n       = in_sizes[0];          // B*L = 409600 (divisible by 256)
    const int nCoarse = in_sizes[3] / DD;     // 10001

    float* out_fused = (float*)d_out;
    float* out_gate  = (float*)d_out + (size_t)n * DD;
    float* hc        = (float*)d_ws;          // nCoarse*32 floats = 1.28 MB

    coarse_mlp_kernel<<<dim3((nCoarse * HH + 255) / 256), dim3(256), 0, stream>>>(
        coarse_W, W1, b1, hc, nCoarse);

    fused_kernel<<<dim3(n / 256), dim3(256), 0, stream>>>(
        fine_ids, coarse_ids, fine_W, coarse_W, freq_W,
        W1, W2, b2, hc, out_fused, out_gate);
}

// Round 8
// 140.188 us; speedup vs baseline: 1.3497x; 1.0086x over previous
//
#include <hip/hip_runtime.h>
#include <math.h>

// FrequencyAwareHierarchicalEmbedding, MI355X/gfx950 — round 8
//
// B*L = 409600, D = 128, H = 32.
// d_in: fine_ids i32, coarse_ids i32, fine_W[1000001*128] f32,
//       coarse_W[10001*128] f32, freq_W[1000001] f32, W1[257*32], b1[32],
//       W2[32], b2[1].
// d_out: fused[BL*128] f32, then adjusted_gate[BL] f32.
//
// Round-8 changes vs round 7 (141.4us):
//  * T14 async-STAGE split: per 64-row chunk, issue next chunk's 16 global
//    row-loads into registers BEFORE the current chunk's MFMA+epilogue,
//    bf16-convert + swizzled ds_write AFTER -> HBM latency hides under
//    compute. Double-buffered 2x16KB LDS tile, one barrier per chunk.
//  * Occupancy 3 -> 4 blocks/CU (launch_bounds(256,4); LDS 36KB, VGPR<=128).
//  * Retained: coalesced row staging (64 lanes x float2 = 512B/instr),
//    XOR-swizzle (byte ^= (row&7)<<4), MFMA 16x16x32_bf16 with W1 B-fragments
//    held in 32 VGPRs all kernel, f32 hc epilogue, shfl_xor butterfly,
//    f32 fusion phase with nontemporal stores.

#define DD 128
#define HH 32

typedef float  f32x4  __attribute__((ext_vector_type(4)));
typedef short  bf16x8 __attribute__((ext_vector_type(8)));

__device__ __forceinline__ float sigmoid_f(float x) {
    return 1.0f / (1.0f + expf(-x));
}

__device__ __forceinline__ unsigned short bf16_rne(float x) {
    union { float f; unsigned u; } c; c.f = x;
    unsigned u = c.u + 0x7fffu + ((c.u >> 16) & 1u);
    return (unsigned short)(u >> 16);
}

// ---------------------------------------------------------------- kernel A --
__global__ __launch_bounds__(256) void coarse_mlp_kernel(
    const float* __restrict__ coarse_W,
    const float* __restrict__ W1,
    const float* __restrict__ b1,
    float* __restrict__ hc,
    int nCoarse)
{
    const int t = blockIdx.x * 256 + threadIdx.x;
    if (t >= nCoarse * HH) return;
    const int r = t >> 5;
    const int j = t & 31;
    const float* __restrict__ row = coarse_W + (size_t)r * DD;
    const float* __restrict__ w   = W1 + DD * HH + j;   // coarse rows of W1
    float acc = b1[j];
    #pragma unroll 8
    for (int i = 0; i < DD; ++i)
        acc = fmaf(row[i], w[i * HH], acc);
    hc[t] = acc;
}

// ---------------------------------------------------------------- kernel B --
__global__ __launch_bounds__(256, 4) void fused_kernel(
    const int*   __restrict__ fine_ids,
    const int*   __restrict__ coarse_ids,
    const float* __restrict__ fine_W,
    const float* __restrict__ coarse_W,
    const float* __restrict__ freq_W,
    const float* __restrict__ W1,
    const float* __restrict__ W2,
    const float* __restrict__ b2,
    const float* __restrict__ hc,
    float* __restrict__ out_fused,
    float* __restrict__ out_gate)
{
    __shared__ __align__(16) unsigned int sX[2][4096];  // 2 x 16KB: 64 rows x 256B
    __shared__ float s_adj[256];
    __shared__ float s_fw[256];
    __shared__ int   s_if[256];
    __shared__ int   s_ic[256];

    const int tid  = threadIdx.x;
    const int lane = tid & 63;
    const int wave = tid >> 6;
    const int P0   = (int)blockIdx.x * 256;

    const int jlo = lane & 15;
    const int kg  = lane >> 4;          // 0..3

    // ---- metadata: ids + freq sigmoid (one position per thread) ---------
    {
        const int p = P0 + tid;
        const int idf = fine_ids[p];
        const int idc = coarse_ids[p];
        s_if[tid] = idf;
        s_ic[tid] = idc;
        s_fw[tid] = sigmoid_f(freq_W[idf]);
    }

    // ---- W1 fine-half B-fragments -> 32 VGPRs, held all kernel ----------
    bf16x8 bfr[2][4];
    #pragma unroll
    for (int n = 0; n < 2; ++n)
        #pragma unroll
        for (int ks = 0; ks < 4; ++ks)
            #pragma unroll
            for (int i = 0; i < 8; ++i) {
                const int k = ks * 32 + kg * 8 + i;
                bfr[n][ks][i] = (short)bf16_rne(W1[k * HH + jlo + 16 * n]);
            }

    // per-lane epilogue constants
    const float w256_0 = W1[2 * DD * HH + jlo];
    const float w256_1 = W1[2 * DD * HH + jlo + 16];
    const float W2_0   = W2[jlo];
    const float W2_1   = W2[jlo + 16];
    const float b2v    = b2[0];

    __syncthreads();    // s_if/s_ic/s_fw ready

    // ---- prologue: stage chunk 0 (wave stages rows wave*16..+16) --------
    float2 rv[16];
    #pragma unroll
    for (int it = 0; it < 16; ++it) {
        const int rr  = wave * 16 + it;
        const int idf = s_if[rr];
        rv[it] = *(const float2*)(fine_W + (size_t)idf * DD + 2 * lane);
    }
    #pragma unroll
    for (int it = 0; it < 16; ++it) {
        const int rr = wave * 16 + it;
        const unsigned pk = (unsigned)bf16_rne(rv[it].x)
                          | ((unsigned)bf16_rne(rv[it].y) << 16);
        *(unsigned*)((char*)&sX[0][0] + rr * 256 + ((4 * lane) ^ ((rr & 7) << 4))) = pk;
    }
    __syncthreads();

    // ---- main loop: 4 chunks of 64 rows, double-buffered ----------------
    #pragma unroll 1
    for (int c = 0; c < 4; ++c) {
        // T14 issue-early: next chunk's global loads (latency hides under compute)
        if (c < 3) {
            #pragma unroll
            for (int it = 0; it < 16; ++it) {
                const int rr  = wave * 16 + it;
                const int idf = s_if[(c + 1) * 64 + rr];
                rv[it] = *(const float2*)(fine_W + (size_t)idf * DD + 2 * lane);
            }
        }

        // compute chunk c: wave owns m-tile `wave` (16 rows)
        const char* bufc = (const char*)&sX[c & 1][0];
        f32x4 acc0 = {0.f, 0.f, 0.f, 0.f};
        f32x4 acc1 = {0.f, 0.f, 0.f, 0.f};
        const int rr = wave * 16 + jlo;              // A row for this lane
        #pragma unroll
        for (int ks = 0; ks < 4; ++ks) {
            const bf16x8 a = *(const bf16x8*)(bufc
                + rr * 256 + ((kg * 16 + ks * 64) ^ ((rr & 7) << 4)));
            acc0 = __builtin_amdgcn_mfma_f32_16x16x32_bf16(a, bfr[0][ks], acc0, 0, 0, 0);
            acc1 = __builtin_amdgcn_mfma_f32_16x16x32_bf16(a, bfr[1][ks], acc1, 0, 0, 0);
        }
        // epilogue: + hc + freq row, relu, @W2, butterfly, sigmoid
        #pragma unroll
        for (int r = 0; r < 4; ++r) {
            const int posl = c * 64 + wave * 16 + kg * 4 + r;   // local 0..255
            const int idc  = s_ic[posl];
            const float fw = s_fw[posl];
            const float* __restrict__ hcrow = hc + idc * HH;
            const float v0 = acc0[r] + hcrow[jlo]      + w256_0 * fw;
            const float v1 = acc1[r] + hcrow[jlo + 16] + w256_1 * fw;
            float tr = fmaxf(v0, 0.f) * W2_0 + fmaxf(v1, 0.f) * W2_1;
            tr += __shfl_xor(tr, 1);
            tr += __shfl_xor(tr, 2);
            tr += __shfl_xor(tr, 4);
            tr += __shfl_xor(tr, 8);
            const float adj = sigmoid_f(tr + b2v) * fw;
            if (jlo == r) s_adj[posl] = adj;
        }

        // T14 write-late: convert + swizzled ds_write of next chunk
        if (c < 3) {
            char* dst = (char*)&sX[(c + 1) & 1][0];
            #pragma unroll
            for (int it = 0; it < 16; ++it) {
                const int rr = wave * 16 + it;
                const unsigned pk = (unsigned)bf16_rne(rv[it].x)
                                  | ((unsigned)bf16_rne(rv[it].y) << 16);
                *(unsigned*)(dst + rr * 256 + ((4 * lane) ^ ((rr & 7) << 4))) = pk;
            }
        }
        __syncthreads();
    }

    // ---- gate output (coalesced) ---------------------------------------
    __builtin_nontemporal_store(s_adj[tid], out_gate + P0 + tid);

    // ---- phase 2: fusion, wave-cooperative (proven) ---------------------
    const int half = lane >> 5;          // 0/1: which slot of the pair
    const int d0   = (lane & 31) * 4;    // 32 lanes cover the 128-float row
    const int waveBase = wave * 64;
    #pragma unroll 1
    for (int q = 0; q < 64; q += 2) {
        const int slot = waveBase + q + half;
        const float a  = s_adj[slot];
        const int   jf = s_if[slot] * DD;
        const int   jc = s_ic[slot] * DD;
        const float4 f = *(const float4*)(fine_W   + (size_t)jf + d0);  // L1/L2 hit
        const float4 c = *(const float4*)(coarse_W + (size_t)jc + d0);  // L2-resident
        f32x4 o;
        o.x = fmaf(a, f.x - c.x, c.x);
        o.y = fmaf(a, f.y - c.y, c.y);
        o.z = fmaf(a, f.z - c.z, c.z);
        o.w = fmaf(a, f.w - c.w, c.w);
        f32x4* dst = (f32x4*)(out_fused + (size_t)(P0 + slot) * DD + d0);
        __builtin_nontemporal_store(o, dst);          // never re-read
    }
}

// ------------------------------------------------------------------- launch --
extern "C" void kernel_launch(void* const* d_in, const int* in_sizes, int n_in,
                              void* d_out, int out_size, void* d_ws, size_t ws_size,
                              hipStream_t stream) {
    const int*   fine_ids   = (const int*)  d_in[0];
    const int*   coarse_ids = (const int*)  d_in[1];
    const float* fine_W     = (const float*)d_in[2];
    const float* coarse_W   = (const float*)d_in[3];
    const float* freq_W     = (const float*)d_in[4];
    const float* W1         = (const float*)d_in[5];
    const float* b1         = (const float*)d_in[6];
    const float* W2         = (const float*)d_in[7];
    const float* b2         = (const float*)d_in[8];

    const int n       = in_sizes[0];          // B*L = 409600 (divisible by 256)
    const int nCoarse = in_sizes[3] / DD;     // 10001

    float* out_fused = (float*)d_out;
    float* out_gate  = (float*)d_out + (size_t)n * DD;
    float* hc        = (float*)d_ws;          // nCoarse*32 floats = 1.28 MB

    coarse_mlp_kernel<<<dim3((nCoarse * HH + 255) / 256), dim3(256), 0, stream>>>(
        coarse_W, W1, b1, hc, nCoarse);

    fused_kernel<<<dim3(n / 256), dim3(256), 0, stream>>>(
        fine_ids, coarse_ids, fine_W, coarse_W, freq_W,
        W1, W2, b2, hc, out_fused, out_gate);
}

// Round 9
// 118.612 us; speedup vs baseline: 1.5952x; 1.1819x over previous
//
#include <hip/hip_runtime.h>
#include <math.h>

// FrequencyAwareHierarchicalEmbedding, MI355X/gfx950 — round 9
//
// B*L = 409600, D = 128, H = 32.
// d_in: fine_ids i32, coarse_ids i32, fine_W[1000001*128] f32,
//       coarse_W[10001*128] f32, freq_W[1000001] f32, W1[257*32], b1[32],
//       W2[32], b2[1].
// d_out: fused[BL*128] f32, then adjusted_gate[BL] f32.
//
// Round-9 structure (vs r8, 140us):
//  * SINGLE-PASS: fine rows are loaded once (f32, coalesced float2/lane),
//    kept in registers rv[16], used for BOTH the bf16 MFMA staging and the
//    final f32 blend. The separate phase-2 fusion loop (and its full re-read
//    of fine rows) is deleted.
//  * BARRIER-FREE: each wave stages into its own private 4KB LDS region and
//    reads only its own rows -> no __syncthreads anywhere. adj broadcast via
//    __shfl with compile-time lane (row-sum uniform across each 16-lane group
//    after the butterfly). Metadata LDS entries are read only by the wave
//    whose lanes wrote them.
//  * Retained: hc precompute (exact f32 coarse half), W1 B-fragments in 32
//    VGPRs all kernel, XOR-swizzled LDS repack, shfl_xor butterfly epilogue,
//    nontemporal output stores.

#define DD 128
#define HH 32

typedef float  f32x2  __attribute__((ext_vector_type(2)));
typedef float  f32x4  __attribute__((ext_vector_type(4)));
typedef short  bf16x8 __attribute__((ext_vector_type(8)));

__device__ __forceinline__ float sigmoid_f(float x) {
    return 1.0f / (1.0f + expf(-x));
}

__device__ __forceinline__ unsigned short bf16_rne(float x) {
    union { float f; unsigned u; } c; c.f = x;
    unsigned u = c.u + 0x7fffu + ((c.u >> 16) & 1u);
    return (unsigned short)(u >> 16);
}

// ---------------------------------------------------------------- kernel A --
__global__ __launch_bounds__(256) void coarse_mlp_kernel(
    const float* __restrict__ coarse_W,
    const float* __restrict__ W1,
    const float* __restrict__ b1,
    float* __restrict__ hc,
    int nCoarse)
{
    const int t = blockIdx.x * 256 + threadIdx.x;
    if (t >= nCoarse * HH) return;
    const int r = t >> 5;
    const int j = t & 31;
    const float* __restrict__ row = coarse_W + (size_t)r * DD;
    const float* __restrict__ w   = W1 + DD * HH + j;   // coarse rows of W1
    float acc = b1[j];
    #pragma unroll 8
    for (int i = 0; i < DD; ++i)
        acc = fmaf(row[i], w[i * HH], acc);
    hc[t] = acc;
}

// ---------------------------------------------------------------- kernel B --
__global__ __launch_bounds__(256, 4) void fused_kernel(
    const int*   __restrict__ fine_ids,
    const int*   __restrict__ coarse_ids,
    const float* __restrict__ fine_W,
    const float* __restrict__ coarse_W,
    const float* __restrict__ freq_W,
    const float* __restrict__ W1,
    const float* __restrict__ W2,
    const float* __restrict__ b2,
    const float* __restrict__ hc,
    float* __restrict__ out_fused,
    float* __restrict__ out_gate)
{
    __shared__ __align__(16) unsigned int sX[4][1024];  // 4KB per wave, private
    __shared__ float s_fw[256];
    __shared__ int   s_if[256];
    __shared__ int   s_ic[256];

    const int tid  = threadIdx.x;
    const int lane = tid & 63;
    const int wave = tid >> 6;
    const int P0   = (int)blockIdx.x * 256;

    const int jlo = lane & 15;
    const int kg  = lane >> 4;          // 0..3

    // ---- metadata (each wave writes & later reads ONLY its own 64 slots) --
    {
        const int p = P0 + tid;
        const int idf = fine_ids[p];
        s_if[tid] = idf;
        s_ic[tid] = coarse_ids[p];
        s_fw[tid] = sigmoid_f(freq_W[idf]);
    }

    // ---- W1 fine-half B-fragments -> 32 VGPRs, held all kernel ----------
    bf16x8 bfr[2][4];
    #pragma unroll
    for (int n = 0; n < 2; ++n)
        #pragma unroll
        for (int ks = 0; ks < 4; ++ks)
            #pragma unroll
            for (int i = 0; i < 8; ++i) {
                const int k = ks * 32 + kg * 8 + i;
                bfr[n][ks][i] = (short)bf16_rne(W1[k * HH + jlo + 16 * n]);
            }

    // per-lane epilogue constants
    const float w256_0 = W1[2 * DD * HH + jlo];
    const float w256_1 = W1[2 * DD * HH + jlo + 16];
    const float W2_0   = W2[jlo];
    const float W2_1   = W2[jlo + 16];
    const float b2v    = b2[0];

    char* const swave = (char*)&sX[wave][0];
    const int wbase = wave * 64;        // wave's first local position

    // ---- main loop: 4 tiles of 16 rows, fully wave-independent ----------
    #pragma unroll 1
    for (int it = 0; it < 4; ++it) {
        const int base = wbase + it * 16;

        // 1. load 16 fine rows, f32, coalesced (64 lanes x float2 = 512B row)
        float2 rv[16];
        #pragma unroll
        for (int i = 0; i < 16; ++i) {
            const int idf = s_if[base + i];
            rv[i] = *(const float2*)(fine_W + (size_t)idf * DD + 2 * lane);
        }

        // 2. bf16-pack + swizzled ds_write into the wave-private region
        #pragma unroll
        for (int i = 0; i < 16; ++i) {
            const unsigned pk = (unsigned)bf16_rne(rv[i].x)
                              | ((unsigned)bf16_rne(rv[i].y) << 16);
            *(unsigned*)(swave + i * 256 + ((4 * lane) ^ ((i & 7) << 4))) = pk;
        }

        // 3. MFMA: X(16x128) @ W1fine(128x32)
        f32x4 acc0 = {0.f, 0.f, 0.f, 0.f};
        f32x4 acc1 = {0.f, 0.f, 0.f, 0.f};
        #pragma unroll
        for (int ks = 0; ks < 4; ++ks) {
            const bf16x8 a = *(const bf16x8*)(swave
                + jlo * 256 + ((kg * 16 + ks * 64) ^ ((jlo & 7) << 4)));
            acc0 = __builtin_amdgcn_mfma_f32_16x16x32_bf16(a, bfr[0][ks], acc0, 0, 0, 0);
            acc1 = __builtin_amdgcn_mfma_f32_16x16x32_bf16(a, bfr[1][ks], acc1, 0, 0, 0);
        }

        // 4. epilogue: + hc + freq row, relu, @W2, butterfly, sigmoid
        float adjv[4];
        #pragma unroll
        for (int r = 0; r < 4; ++r) {
            const int posl = base + kg * 4 + r;
            const int idc  = s_ic[posl];
            const float fw = s_fw[posl];
            const float* __restrict__ hcrow = hc + idc * HH;
            const float v0 = acc0[r] + hcrow[jlo]      + w256_0 * fw;
            const float v1 = acc1[r] + hcrow[jlo + 16] + w256_1 * fw;
            float tr = fmaxf(v0, 0.f) * W2_0 + fmaxf(v1, 0.f) * W2_1;
            tr += __shfl_xor(tr, 1);
            tr += __shfl_xor(tr, 2);
            tr += __shfl_xor(tr, 4);
            tr += __shfl_xor(tr, 8);
            adjv[r] = sigmoid_f(tr + b2v) * fw;       // uniform across jlo group
            if (jlo == r)
                __builtin_nontemporal_store(adjv[r], out_gate + P0 + posl);
        }

        // 5. blend from rv (exact f32) + coarse gather, nt store
        #pragma unroll
        for (int i = 0; i < 16; ++i) {
            const float a = __shfl(adjv[i & 3], ((i >> 2) << 4) + (i & 3));
            const int idc = s_ic[base + i];
            const float2 c2 = *(const float2*)(coarse_W + (size_t)idc * DD + 2 * lane);
            f32x2 o;
            o.x = fmaf(a, rv[i].x - c2.x, c2.x);
            o.y = fmaf(a, rv[i].y - c2.y, c2.y);
            f32x2* dst = (f32x2*)(out_fused + (size_t)(P0 + base + i) * DD + 2 * lane);
            __builtin_nontemporal_store(o, dst);      // 512B/row, coalesced
        }
    }
}

// ------------------------------------------------------------------- launch --
extern "C" void kernel_launch(void* const* d_in, const int* in_sizes, int n_in,
                              void* d_out, int out_size, void* d_ws, size_t ws_size,
                              hipStream_t stream) {
    const int*   fine_ids   = (const int*)  d_in[0];
    const int*   coarse_ids = (const int*)  d_in[1];
    const float* fine_W     = (const float*)d_in[2];
    const float* coarse_W   = (const float*)d_in[3];
    const float* freq_W     = (const float*)d_in[4];
    const float* W1         = (const float*)d_in[5];
    const float* b1         = (const float*)d_in[6];
    const float* W2         = (const float*)d_in[7];
    const float* b2         = (const float*)d_in[8];

    const int n       = in_sizes[0];          // B*L = 409600 (divisible by 256)
    const int nCoarse = in_sizes[3] / DD;     // 10001

    float* out_fused = (float*)d_out;
    float* out_gate  = (float*)d_out + (size_t)n * DD;
    float* hc        = (float*)d_ws;          // nCoarse*32 floats = 1.28 MB

    coarse_mlp_kernel<<<dim3((nCoarse * HH + 255) / 256), dim3(256), 0, stream>>>(
        coarse_W, W1, b1, hc, nCoarse);

    fused_kernel<<<dim3(n / 256), dim3(256), 0, stream>>>(
        fine_ids, coarse_ids, fine_W, coarse_W, freq_W,
        W1, W2, b2, hc, out_fused, out_gate);
}